// Round 7
// baseline (1080.041 us; speedup 1.0000x reference)
//
#include <hip/hip_runtime.h>

// y[b,o] = sum_i x[b,i]*W[i,o]*w_mask[b,i,o] + bias[o]*b_mask[b,o]
// B=32, IN_F=1024, OUT_F=4096. f32 tensors, int32 masks.
//
// R7 = CALIBRATION ROUND. R2-R6: five structurally different kernels all in
// 676-702 us. Either kernel ~170 us with 2x headroom (fixed cost ~511 us) or
// kernel ~90 us at the HBM roofline (fixed ~590 us) — the profile can't
// distinguish (restore copy <334 us only bounds fixed to [511,677]).
// This round launches the IDENTICAL R6 main kernel 5x (idempotent: partial
// fully overwritten each pass; same work every call, graph-safe).
//   K_main = (dur_R7 - dur_R6) / 4.
// ~1370 us => headroom exists; ~1070 us => R6 was already at roofline.

#define B_DIM 32
#define IN_F 1024
#define OUT_F 4096
#define BO (B_DIM * OUT_F)        // 131072
#define I_CHUNK 64
#define N_CHUNK (IN_F / I_CHUNK)  // 16

typedef int   v4i __attribute__((ext_vector_type(4)));
typedef float v4f __attribute__((ext_vector_type(4)));

// partial[chunk][b][o] : 16 x 32 x 4096 f32 = 8 MiB in d_ws
__global__ __launch_bounds__(256, 2) void masked_gemv_partial(
    const float* __restrict__ x,       // [B, IN_F]
    const float* __restrict__ weight,  // [IN_F, OUT_F]
    const int* __restrict__ w_mask,    // [B, IN_F, OUT_F]
    float* __restrict__ partial)
{
    const int bid   = blockIdx.x;
    const int b     = bid >> 4;
    const int chunk = bid & 15;
    const int i0    = chunk * I_CHUNK;

    __shared__ float xs[I_CHUNK];      // 256 B
    if (threadIdx.x < I_CHUNK) xs[threadIdx.x] = x[b * IN_F + i0 + threadIdx.x];
    __syncthreads();

    const int o4 = threadIdx.x << 2;
    const int* __restrict__ mrow =
        w_mask + ((size_t)b * IN_F + i0) * OUT_F + o4;
    const float* __restrict__ wrow = weight + (size_t)i0 * OUT_F + o4;

    v4f acc0 = {0,0,0,0}, acc1 = {0,0,0,0}, acc2 = {0,0,0,0}, acc3 = {0,0,0,0};

#pragma unroll 2
    for (int i = 0; i < I_CHUNK; ++i) {
        const float xi = xs[i];                       // wave-uniform broadcast
        const size_t r = (size_t)i * OUT_F;
        const v4i m0 = __builtin_nontemporal_load((const v4i*)(mrow + r));
        const v4i m1 = __builtin_nontemporal_load((const v4i*)(mrow + r + 1024));
        const v4i m2 = __builtin_nontemporal_load((const v4i*)(mrow + r + 2048));
        const v4i m3 = __builtin_nontemporal_load((const v4i*)(mrow + r + 3072));
        const v4f w0 = *(const v4f*)(wrow + r);
        const v4f w1 = *(const v4f*)(wrow + r + 1024);
        const v4f w2 = *(const v4f*)(wrow + r + 2048);
        const v4f w3 = *(const v4f*)(wrow + r + 3072);
        acc0.x = fmaf(m0.x ? xi : 0.f, w0.x, acc0.x);
        acc0.y = fmaf(m0.y ? xi : 0.f, w0.y, acc0.y);
        acc0.z = fmaf(m0.z ? xi : 0.f, w0.z, acc0.z);
        acc0.w = fmaf(m0.w ? xi : 0.f, w0.w, acc0.w);
        acc1.x = fmaf(m1.x ? xi : 0.f, w1.x, acc1.x);
        acc1.y = fmaf(m1.y ? xi : 0.f, w1.y, acc1.y);
        acc1.z = fmaf(m1.z ? xi : 0.f, w1.z, acc1.z);
        acc1.w = fmaf(m1.w ? xi : 0.f, w1.w, acc1.w);
        acc2.x = fmaf(m2.x ? xi : 0.f, w2.x, acc2.x);
        acc2.y = fmaf(m2.y ? xi : 0.f, w2.y, acc2.y);
        acc2.z = fmaf(m2.z ? xi : 0.f, w2.z, acc2.z);
        acc2.w = fmaf(m2.w ? xi : 0.f, w2.w, acc2.w);
        acc3.x = fmaf(m3.x ? xi : 0.f, w3.x, acc3.x);
        acc3.y = fmaf(m3.y ? xi : 0.f, w3.y, acc3.y);
        acc3.z = fmaf(m3.z ? xi : 0.f, w3.z, acc3.z);
        acc3.w = fmaf(m3.w ? xi : 0.f, w3.w, acc3.w);
    }

    float* prow = partial + ((size_t)chunk * B_DIM + b) * OUT_F + o4;
    __builtin_nontemporal_store(acc0, (v4f*)(prow));
    __builtin_nontemporal_store(acc1, (v4f*)(prow + 1024));
    __builtin_nontemporal_store(acc2, (v4f*)(prow + 2048));
    __builtin_nontemporal_store(acc3, (v4f*)(prow + 3072));
}

__global__ __launch_bounds__(256) void reduce_bias_kernel(
    const float* __restrict__ partial,  // [N_CHUNK][B][OUT_F]
    const float* __restrict__ bias,     // [OUT_F]
    const int* __restrict__ b_mask,     // [B, OUT_F]
    float* __restrict__ out)            // [B, OUT_F]
{
    const int tid = blockIdx.x * 256 + threadIdx.x;  // [0, BO)
    float s = 0.f;
#pragma unroll
    for (int c = 0; c < N_CHUNK; ++c)
        s += partial[(size_t)c * BO + tid];
    const int o = tid & (OUT_F - 1);
    out[tid] = fmaf(bias[o], (float)b_mask[tid], s);
}

extern "C" void kernel_launch(void* const* d_in, const int* in_sizes, int n_in,
                              void* d_out, int out_size, void* d_ws, size_t ws_size,
                              hipStream_t stream) {
    const float* x      = (const float*)d_in[0];
    const float* weight = (const float*)d_in[1];
    const float* bias   = (const float*)d_in[2];
    const int*   w_mask = (const int*)d_in[3];
    const int*   b_mask = (const int*)d_in[4];
    float* out     = (float*)d_out;
    float* partial = (float*)d_ws;  // 8 MiB used

    // CALIBRATION: 5 identical idempotent launches; K = (dur_R7 - dur_R6)/4.
    for (int rep = 0; rep < 5; ++rep) {
        masked_gemv_partial<<<B_DIM * N_CHUNK, 256, 0, stream>>>(
            x, weight, w_mask, partial);
    }
    reduce_bias_kernel<<<BO / 256, 256, 0, stream>>>(partial, bias, b_mask, out);
}

// Round 8
// 679.605 us; speedup vs baseline: 1.5892x; 1.5892x over previous
//
#include <hip/hip_runtime.h>

// y[b,o] = sum_i x[b,i]*W[i,o]*w_mask[b,i,o] + bias[o]*b_mask[b,o]
// B=32, IN_F=1024, OUT_F=4096. f32 tensors, int32 masks.
//
// FINAL (R8, post-calibration). R7 measured: main kernel = (1080.0-691.2)/4
// = 97.2 us for ~561 MB => 5.8 TB/s = 92% of achievable HBM BW (harness fill
// = 6.5 TB/s). Fixed harness cost (poison+restore) = ~591 us of every dur_us
// and is untouchable. Mask (512 MiB) is irreducible read-once traffic =>
// ~85 us hard floor; remaining headroom <= 12 us, inside the +/-13 us noise
// band. This is the R4 variant (best measured total, 676.5 us): 4-way
// split-K, int4 mask loads (1 KiB/wave-instr), nt hints, 2 MiB partials.

#define B_DIM 32
#define IN_F 1024
#define OUT_F 4096
#define N_CHUNK 4
#define I_CHUNK (IN_F / N_CHUNK)   // 256 i-rows per block
#define BO (B_DIM * OUT_F)         // 131072

typedef int   v4i __attribute__((ext_vector_type(4)));
typedef float v4f __attribute__((ext_vector_type(4)));

// partial[chunk][b][o] : 4 x 32 x 4096 f32 = 2 MiB in d_ws
__global__ __launch_bounds__(256, 2) void masked_gemv_partial(
    const float* __restrict__ x,       // [B, IN_F]
    const float* __restrict__ weight,  // [IN_F, OUT_F]
    const int* __restrict__ w_mask,    // [B, IN_F, OUT_F]
    float* __restrict__ partial)
{
    const int bid   = blockIdx.x;      // b*16 + o_blk*4 + chunk
    const int b     = bid >> 4;
    const int s     = bid & 15;
    const int o_blk = s >> 2;
    const int chunk = s & 3;
    const int i0    = chunk * I_CHUNK;
    const int o     = o_blk * 1024 + (threadIdx.x << 2);

    __shared__ float xs[I_CHUNK];      // 1 KiB
    xs[threadIdx.x] = x[b * IN_F + i0 + threadIdx.x];
    __syncthreads();

    const int*   mptr = w_mask + (size_t)b * IN_F * OUT_F + (size_t)i0 * OUT_F + o;
    const float* wptr = weight + (size_t)i0 * OUT_F + o;

    v4f acc = {0.f, 0.f, 0.f, 0.f};
#pragma unroll 8
    for (int i = 0; i < I_CHUNK; ++i) {
        const float xi = xs[i];  // wave-uniform -> LDS broadcast
        const v4i m = __builtin_nontemporal_load((const v4i*)(mptr + (size_t)i * OUT_F));
        const v4f w = *(const v4f*)(wptr + (size_t)i * OUT_F);
        acc.x = fmaf(m.x ? xi : 0.f, w.x, acc.x);
        acc.y = fmaf(m.y ? xi : 0.f, w.y, acc.y);
        acc.z = fmaf(m.z ? xi : 0.f, w.z, acc.z);
        acc.w = fmaf(m.w ? xi : 0.f, w.w, acc.w);
    }

    __builtin_nontemporal_store(acc,
        (v4f*)(partial + (size_t)chunk * BO + b * OUT_F + o));
}

__global__ __launch_bounds__(256) void reduce_bias_kernel(
    const float* __restrict__ partial,  // [N_CHUNK][B][OUT_F]
    const float* __restrict__ bias,     // [OUT_F]
    const int* __restrict__ b_mask,     // [B, OUT_F]
    float* __restrict__ out)            // [B, OUT_F]
{
    const int tid = blockIdx.x * 256 + threadIdx.x;  // [0, BO)
    float s0 = partial[tid]                  + partial[(size_t)1 * BO + tid];
    float s1 = partial[(size_t)2 * BO + tid] + partial[(size_t)3 * BO + tid];
    const int o = tid & (OUT_F - 1);
    out[tid] = fmaf(bias[o], (float)b_mask[tid], s0 + s1);
}

extern "C" void kernel_launch(void* const* d_in, const int* in_sizes, int n_in,
                              void* d_out, int out_size, void* d_ws, size_t ws_size,
                              hipStream_t stream) {
    const float* x      = (const float*)d_in[0];
    const float* weight = (const float*)d_in[1];
    const float* bias   = (const float*)d_in[2];
    const int*   w_mask = (const int*)d_in[3];
    const int*   b_mask = (const int*)d_in[4];
    float* out     = (float*)d_out;
    float* partial = (float*)d_ws;  // 2 MiB used

    masked_gemv_partial<<<B_DIM * 16, 256, 0, stream>>>(x, weight, w_mask, partial);
    reduce_bias_kernel<<<BO / 256, 256, 0, stream>>>(partial, bias, b_mask, out);
}